// Round 1
// baseline (334.246 us; speedup 1.0000x reference)
//
#include <hip/hip_runtime.h>
#include <hip/hip_bf16.h>
#include <stdint.h>

// ---------------- problem constants ----------------
#define BATCH   16384
#define SDIM    128
#define ENCK    10
#define ADIM    32
#define DECK    10
#define HID     2048
#define KSPINE  1280      // SDIM*ENCK
#define NOUT3   320       // ADIM*DECK
#define NPAD    384       // padded to multiple of 128

typedef __bf16 bf16x8 __attribute__((ext_vector_type(8)));
typedef float  f32x4  __attribute__((ext_vector_type(4)));

typedef __attribute__((address_space(1))) const void kGlobalVoid;
typedef __attribute__((address_space(3))) void       kLdsVoid;

__device__ __forceinline__ unsigned short f2b(float f) {
  union { float f; unsigned u; } v; v.f = f;
  unsigned r = v.u + 0x7fffu + ((v.u >> 16) & 1u);   // RNE
  return (unsigned short)(r >> 16);
}

// ---------------- fp32 -> bf16 convert (2 elems/thread) ----------------
__global__ void f2b_kernel(const float* __restrict__ in, unsigned* __restrict__ out, int n2) {
  int i = blockIdx.x * blockDim.x + threadIdx.x;
  if (i >= n2) return;
  float2 v = reinterpret_cast<const float2*>(in)[i];
  out[i] = (unsigned)f2b(v.x) | ((unsigned)f2b(v.y) << 16);
}

// ---------------- encoder: sigmoid((x-mean)/std) -> bf16 spine ----------------
__global__ void encoder_kernel(const float* __restrict__ state,
                               const float* __restrict__ mean,
                               const float* __restrict__ stdv,
                               unsigned* __restrict__ spine) {  // [BATCH*SDIM*ENCK] bf16 as uint pairs
  int idx = blockIdx.x * blockDim.x + threadIdx.x;   // b*SDIM + d
  if (idx >= BATCH * SDIM) return;
  int d = idx & (SDIM - 1);
  float x = state[idx];
  float vals[ENCK];
#pragma unroll
  for (int k = 0; k < ENCK; ++k) {
    float z = (x - mean[d * ENCK + k]) / stdv[d * ENCK + k];
    vals[k] = 1.f / (1.f + __expf(-z));
  }
  unsigned* dst = spine + idx * (ENCK / 2);          // idx*10 bf16 = idx*5 uints
#pragma unroll
  for (int k = 0; k < ENCK / 2; ++k)
    dst[k] = (unsigned)f2b(vals[2 * k]) | ((unsigned)f2b(vals[2 * k + 1]) << 16);
}

// ---------------- bf16 GEMM: C[M,N] = A[M,K] * Bw[N,K]^T (+bias, relu) ----------------
// 128x128 tile, BK=64, 4 waves (2x2), 4x4 fragments of mfma_f32_16x16x32_bf16 per wave.
// global_load_lds(16B) staging: linear LDS dest + inverse-swizzled global source;
// ds_read_b128 fragment reads with st-style XOR swizzle (byte ^= (row&7)<<4).
template <bool RELU, bool OUTBF16>
__global__ __launch_bounds__(256) void gemm_bt(
    const unsigned short* __restrict__ A,    // [M,K] bf16
    const unsigned short* __restrict__ Bw,   // [N,K] bf16 (weights, row-major [N,K])
    const float* __restrict__ bias,          // [nbias] fp32
    void* __restrict__ Cout,                 // [M,ldc] bf16 or fp32
    int K, int ldc, int nbias) {
  __shared__ char smem[32768];
  char* As = smem;            // 128 x 64 bf16, swizzled
  char* Bs = smem + 16384;

  const int t    = threadIdx.x;
  const int lane = t & 63;
  const int w    = t >> 6;
  const int wr   = w >> 1;     // wave row (0..1)
  const int wc   = w & 1;      // wave col (0..1)
  const int lr   = lane & 15;  // fragment row/col within 16
  const int kh   = lane >> 4;  // k-chunk selector (0..3)

  const int row0 = blockIdx.x * 128;
  const int col0 = blockIdx.y * 128;

  f32x4 acc[4][4];
#pragma unroll
  for (int m = 0; m < 4; ++m)
#pragma unroll
    for (int n = 0; n < 4; ++n)
      acc[m][n] = (f32x4){0.f, 0.f, 0.f, 0.f};

  for (int kt = 0; kt < K; kt += 64) {
    // ---- stage A,B tiles (128x64 bf16 each) via global_load_lds, 16B/lane x4 ----
#pragma unroll
    for (int i = 0; i < 4; ++i) {
      int p  = i * 4096 + t * 16;                 // linear LDS byte
      int r  = p >> 7;                            // tile row (128B per row)
      int cb = (p & 127) ^ ((r & 7) << 4);        // inverse-swizzled column byte
      const unsigned short* sa = A  + (size_t)(row0 + r) * K + kt + (cb >> 1);
      const unsigned short* sb = Bw + (size_t)(col0 + r) * K + kt + (cb >> 1);
      __builtin_amdgcn_global_load_lds((kGlobalVoid*)sa, (kLdsVoid*)(As + p), 16, 0, 0);
      __builtin_amdgcn_global_load_lds((kGlobalVoid*)sb, (kLdsVoid*)(Bs + p), 16, 0, 0);
    }
    asm volatile("s_waitcnt vmcnt(0)" ::: "memory");
    __syncthreads();

    // ---- compute: 2 k-slices x 16 MFMA ----
#pragma unroll
    for (int ks = 0; ks < 64; ks += 32) {
      bf16x8 af[4], bfv[4];
#pragma unroll
      for (int m = 0; m < 4; ++m) {
        int row  = wr * 64 + m * 16 + lr;
        int byte = (row * 128 + ks * 2 + kh * 16) ^ ((row & 7) << 4);
        af[m] = *reinterpret_cast<const bf16x8*>(As + byte);
      }
#pragma unroll
      for (int n = 0; n < 4; ++n) {
        int row  = wc * 64 + n * 16 + lr;
        int byte = (row * 128 + ks * 2 + kh * 16) ^ ((row & 7) << 4);
        bfv[n] = *reinterpret_cast<const bf16x8*>(Bs + byte);
      }
#pragma unroll
      for (int m = 0; m < 4; ++m)
#pragma unroll
        for (int n = 0; n < 4; ++n)
          acc[m][n] = __builtin_amdgcn_mfma_f32_16x16x32_bf16(af[m], bfv[n], acc[m][n], 0, 0, 0);
    }
    __syncthreads();
  }

  // ---- epilogue: bias (+relu), store. C/D layout: col=lane&15, row=(lane>>4)*4+v ----
#pragma unroll
  for (int m = 0; m < 4; ++m) {
    int gr0 = row0 + wr * 64 + m * 16 + kh * 4;
#pragma unroll
    for (int n = 0; n < 4; ++n) {
      int gc = col0 + wc * 64 + n * 16 + lr;
      float bv = (gc < nbias) ? bias[gc] : 0.f;
#pragma unroll
      for (int v = 0; v < 4; ++v) {
        float val = acc[m][n][v] + bv;
        if (RELU) val = fmaxf(val, 0.f);
        size_t off = (size_t)(gr0 + v) * ldc + gc;
        if (OUTBF16) ((unsigned short*)Cout)[off] = f2b(val);
        else         ((float*)Cout)[off] = val;
      }
    }
  }
}

// ---------------- decoder: per-channel 10-tap dot + tanh ----------------
__global__ void decoder_kernel(const float* __restrict__ out3,   // [BATCH, NPAD] fp32
                               const float* __restrict__ Wd,     // [ADIM, DECK]
                               const float* __restrict__ bd,     // [ADIM]
                               float* __restrict__ out) {        // [BATCH, ADIM]
  int idx = blockIdx.x * blockDim.x + threadIdx.x;  // b*ADIM + a
  if (idx >= BATCH * ADIM) return;
  int b = idx >> 5, a = idx & 31;
  const float* p = out3 + (size_t)b * NPAD + a * DECK;
  float acc = bd[a];
#pragma unroll
  for (int k = 0; k < DECK; ++k) acc += p[k] * Wd[a * DECK + k];
  out[idx] = tanhf(acc);
}

// ---------------- launch ----------------
extern "C" void kernel_launch(void* const* d_in, const int* in_sizes, int n_in,
                              void* d_out, int out_size, void* d_ws, size_t ws_size,
                              hipStream_t stream) {
  const float* state    = (const float*)d_in[0];
  const float* mean_enc = (const float*)d_in[1];
  const float* std_enc  = (const float*)d_in[2];
  const float* W1 = (const float*)d_in[3];
  const float* b1 = (const float*)d_in[4];
  const float* W2 = (const float*)d_in[5];
  const float* b2 = (const float*)d_in[6];
  const float* W3 = (const float*)d_in[7];
  const float* b3 = (const float*)d_in[8];
  const float* Wd = (const float*)d_in[9];
  const float* bd = (const float*)d_in[10];

  char* ws = (char*)d_ws;
  // layout (bytes):
  unsigned short* W1b   = (unsigned short*)(ws + 0);          //  5,242,880
  unsigned short* W2b   = (unsigned short*)(ws + 5242880);    //  8,388,608
  unsigned short* W3b   = (unsigned short*)(ws + 13631488);   //  1,572,864 (384x2048, pad zeroed)
  unsigned short* spine = (unsigned short*)(ws + 15204352);   // 41,943,040
  float*          out3  = (float*)(ws + 15204352);            // 25,165,824 (aliases dead spine)
  unsigned short* h1    = (unsigned short*)(ws + 57147392);   // 67,108,864
  unsigned short* h2    = (unsigned short*)(ws + 124256256);  // 67,108,864  (end ~191.4MB)

  // weight converts fp32 -> bf16
  f2b_kernel<<<5120, 256, 0, stream>>>(W1, (unsigned*)W1b, 1310720);
  f2b_kernel<<<8192, 256, 0, stream>>>(W2, (unsigned*)W2b, 2097152);
  f2b_kernel<<<1280, 256, 0, stream>>>(W3, (unsigned*)W3b, 327680);
  hipMemsetAsync(W3b + (size_t)NOUT3 * HID, 0, (size_t)(NPAD - NOUT3) * HID * 2, stream);

  // encoder
  encoder_kernel<<<(BATCH * SDIM) / 256, 256, 0, stream>>>(state, mean_enc, std_enc, (unsigned*)spine);

  // GEMM chain
  gemm_bt<true,  true ><<<dim3(BATCH / 128, HID / 128),  256, 0, stream>>>(spine, W1b, b1, h1,  KSPINE, HID,  HID);
  gemm_bt<true,  true ><<<dim3(BATCH / 128, HID / 128),  256, 0, stream>>>(h1,    W2b, b2, h2,  HID,    HID,  HID);
  gemm_bt<false, false><<<dim3(BATCH / 128, NPAD / 128), 256, 0, stream>>>(h2,    W3b, b3, out3, HID,   NPAD, NOUT3);

  // decoder
  decoder_kernel<<<(BATCH * ADIM) / 256, 256, 0, stream>>>(out3, Wd, bd, (float*)d_out);
}

// Round 2
// 269.750 us; speedup vs baseline: 1.2391x; 1.2391x over previous
//
#include <hip/hip_runtime.h>
#include <hip/hip_bf16.h>
#include <stdint.h>

// ---------------- problem constants ----------------
#define BATCH   16384
#define SDIM    128
#define ENCK    10
#define ADIM    32
#define DECK    10
#define HID     2048
#define KSPINE  1280      // SDIM*ENCK

typedef __bf16 bf16x8 __attribute__((ext_vector_type(8)));
typedef float  f32x4  __attribute__((ext_vector_type(4)));

typedef __attribute__((address_space(1))) const void kGlobalVoid;
typedef __attribute__((address_space(3))) void       kLdsVoid;

__device__ __forceinline__ unsigned short f2b(float f) {
  union { float f; unsigned u; } v; v.f = f;
  unsigned r = v.u + 0x7fffu + ((v.u >> 16) & 1u);   // RNE
  return (unsigned short)(r >> 16);
}

// ---------------- fp32 -> bf16 convert (2 elems/thread) ----------------
__global__ void f2b_kernel(const float* __restrict__ in, unsigned* __restrict__ out, int n2) {
  int i = blockIdx.x * blockDim.x + threadIdx.x;
  if (i >= n2) return;
  float2 v = reinterpret_cast<const float2*>(in)[i];
  out[i] = (unsigned)f2b(v.x) | ((unsigned)f2b(v.y) << 16);
}

// ---------------- encoder: sigmoid((x-mean)/std) -> bf16 spine ----------------
__global__ void encoder_kernel(const float* __restrict__ state,
                               const float* __restrict__ mean,
                               const float* __restrict__ stdv,
                               unsigned* __restrict__ spine) {
  int idx = blockIdx.x * blockDim.x + threadIdx.x;   // b*SDIM + d
  if (idx >= BATCH * SDIM) return;
  int d = idx & (SDIM - 1);
  float x = state[idx];
  float vals[ENCK];
#pragma unroll
  for (int k = 0; k < ENCK; ++k) {
    float z = (x - mean[d * ENCK + k]) / stdv[d * ENCK + k];
    vals[k] = 1.f / (1.f + __expf(-z));
  }
  unsigned* dst = spine + idx * (ENCK / 2);
#pragma unroll
  for (int k = 0; k < ENCK / 2; ++k)
    dst[k] = (unsigned)f2b(vals[2 * k]) | ((unsigned)f2b(vals[2 * k + 1]) << 16);
}

// ---------------- Weff/beff builders: fold grouped-conv into W3 ----------------
__global__ void weff_kernel(const float* __restrict__ W3, const float* __restrict__ Wd,
                            unsigned short* __restrict__ Weff) {
  int idx = blockIdx.x * 256 + threadIdx.x;   // a*2048 + j, 65536 total
  int a = idx >> 11, j = idx & 2047;
  float s = 0.f;
#pragma unroll
  for (int k = 0; k < DECK; ++k)
    s += Wd[a * DECK + k] * W3[(size_t)(a * DECK + k) * HID + j];
  Weff[idx] = f2b(s);
}

__global__ void beff_kernel(const float* __restrict__ b3, const float* __restrict__ Wd,
                            const float* __restrict__ bd, float* __restrict__ beff) {
  int a = threadIdx.x;
  if (a >= ADIM) return;
  float s = bd[a];
#pragma unroll
  for (int k = 0; k < DECK; ++k) s += Wd[a * DECK + k] * b3[a * DECK + k];
  beff[a] = s;
}

// ---------------- 256x256 8-phase bf16 GEMM (T2+T3+T4+T5) ----------------
// C[M,2048] = relu(A[M,K] * Bw[2048,K]^T + bias), bf16 out.
// 512 thr = 8 waves (2M x 4N); per-wave 128x64 out = acc[8][4] f32x4.
// LDS 128 KiB: buf{0,1} x (A 32K + B 32K), rows of 64 bf16 (128B), XOR-swizzled.
// Phase p computes m-pair (p&3) over all 4 n-frags x 2 kslices = 16 MFMA.
// B fragments reg-cached at P1/P5 (so B-LDS is restageable from P2/P6 on).
// Stage order per iter: P1:buf1.Aq2q3<-t1 | P2,P3:buf0.B<-t2 | P4:buf0.Aq0q1<-t2
//                       P5:buf0.Aq2q3<-t2 | P6,P7:buf1.B<-t3 | P8:buf1.Aq0q1<-t3
// vmcnt(6) before closing barrier of P4 and P8 (retire all but 3 newest stages).

#define A0B 0
#define B0B 32768
#define A1B 65536
#define B1B 98304

#define FENCE asm volatile("" ::: "memory")

#define STAGE(BASEPTR, R0A, R0B, LDS0, LDS1, KT)                                             \
  __builtin_amdgcn_global_load_lds((kGlobalVoid*)((BASEPTR) + (size_t)((R0A) + rs) * K + (KT) + ce), \
                                   (kLdsVoid*)(smem + (LDS0) + t * 16), 16, 0, 0);           \
  __builtin_amdgcn_global_load_lds((kGlobalVoid*)((BASEPTR) + (size_t)((R0B) + rs) * K + (KT) + ce), \
                                   (kLdsVoid*)(smem + (LDS1) + t * 16), 16, 0, 0);

#define PHASE(mp, ABASE, DOB, BBASE, DOVM, STAGES)                                           \
  do {                                                                                       \
    bf16x8 af[2][2];                                                                         \
    _Pragma("unroll")                                                                        \
    for (int j = 0; j < 2; ++j) {                                                            \
      _Pragma("unroll")                                                                      \
      for (int ks = 0; ks < 2; ++ks) {                                                       \
        int rowl = wr * 128 + ((mp) * 2 + j) * 16 + lr;                                      \
        af[j][ks] = *reinterpret_cast<const bf16x8*>(                                        \
            smem + (ABASE) + rowl * 128 + ((((ks) << 6) | (kh << 4)) ^ swz));                \
      }                                                                                      \
    }                                                                                        \
    if (DOB) {                                                                               \
      _Pragma("unroll")                                                                      \
      for (int n = 0; n < 4; ++n) {                                                          \
        _Pragma("unroll")                                                                    \
        for (int ks = 0; ks < 2; ++ks) {                                                     \
          int rowl = wc * 64 + n * 16 + lr;                                                  \
          bfv[n][ks] = *reinterpret_cast<const bf16x8*>(                                     \
              smem + (BBASE) + rowl * 128 + ((((ks) << 6) | (kh << 4)) ^ swz));              \
        }                                                                                    \
      }                                                                                      \
    }                                                                                        \
    STAGES                                                                                   \
    FENCE;                                                                                   \
    __builtin_amdgcn_s_barrier();                                                            \
    asm volatile("s_waitcnt lgkmcnt(0)" ::: "memory");                                       \
    __builtin_amdgcn_sched_barrier(0);                                                       \
    __builtin_amdgcn_s_setprio(1);                                                           \
    _Pragma("unroll")                                                                        \
    for (int j = 0; j < 2; ++j)                                                              \
      _Pragma("unroll")                                                                      \
      for (int n = 0; n < 4; ++n)                                                            \
        _Pragma("unroll")                                                                    \
        for (int ks = 0; ks < 2; ++ks)                                                       \
          acc[(mp) * 2 + j][n] =                                                             \
              __builtin_amdgcn_mfma_f32_16x16x32_bf16(af[j][ks], bfv[n][ks],                 \
                                                      acc[(mp) * 2 + j][n], 0, 0, 0);        \
    __builtin_amdgcn_s_setprio(0);                                                           \
    if (DOVM) asm volatile("s_waitcnt vmcnt(6)" ::: "memory");                               \
    FENCE;                                                                                   \
    __builtin_amdgcn_s_barrier();                                                            \
  } while (0)

__global__ __launch_bounds__(512, 2) void gemm256(
    const unsigned short* __restrict__ A,    // [M,K] bf16
    const unsigned short* __restrict__ Bw,   // [2048,K] bf16
    const float* __restrict__ bias,          // [2048]
    unsigned short* __restrict__ Cout,       // [M,2048] bf16
    int K, int NI) {                         // NI = K/128
  __shared__ char smem[131072];

  const int t    = threadIdx.x;
  const int lane = t & 63;
  const int w    = t >> 6;
  const int wr   = w >> 2;      // 0..1
  const int wc   = w & 3;       // 0..3
  const int lr   = lane & 15;
  const int kh   = lane >> 4;   // 0..3
  const int swz  = (lr & 7) << 4;
  const int rs   = t >> 3;                      // stage row within 64-row band
  const int ce   = ((t & 7) ^ (rs & 7)) << 3;   // inverse-swizzled col (elements)

  // XCD-aware swizzle: 512 wgs, 8 XCDs -> XCD x owns N-panel by=x (B L2-resident)
  const int bid = blockIdx.x;
  const int s   = (bid & 7) * 64 + (bid >> 3);
  const int row0 = (s & 63) * 256;
  const int col0 = (s >> 6) * 256;

  f32x4 acc[8][4];
#pragma unroll
  for (int m = 0; m < 8; ++m)
#pragma unroll
    for (int n = 0; n < 4; ++n)
      acc[m][n] = (f32x4){0.f, 0.f, 0.f, 0.f};

  bf16x8 bfv[4][2];

  // ---- prologue: buf0 <- tile0 (4 stages), buf1 <- tile1 B + Aq0q1 (3 stages) ----
  STAGE(Bw, col0 + 0,   col0 + 64,  B0B + 0,     B0B + 8192,  0);
  STAGE(Bw, col0 + 128, col0 + 192, B0B + 16384, B0B + 24576, 0);
  STAGE(A,  row0 + 0,   row0 + 128, A0B + 0,     A0B + 16384, 0);
  STAGE(A,  row0 + 64,  row0 + 192, A0B + 8192,  A0B + 24576, 0);
  STAGE(Bw, col0 + 0,   col0 + 64,  B1B + 0,     B1B + 8192,  64);
  STAGE(Bw, col0 + 128, col0 + 192, B1B + 16384, B1B + 24576, 64);
  STAGE(A,  row0 + 0,   row0 + 128, A1B + 0,     A1B + 16384, 64);
  asm volatile("s_waitcnt vmcnt(6)" ::: "memory");
  FENCE;
  __builtin_amdgcn_s_barrier();

  for (int i = 0; i < NI; ++i) {
    int kt0 = i << 7;
    int kt1 = kt0 + 64;
    int kt2 = kt0 + 128; if (kt2 >= K) kt2 -= K;   // wrapped prefetch on last iter (unused)
    int kt3 = kt0 + 192; if (kt3 >= K) kt3 -= K;

    PHASE(0, A0B, true,  B0B, false, STAGE(A,  row0 + 64,  row0 + 192, A1B + 8192,  A1B + 24576, kt1));
    PHASE(1, A0B, false, B0B, false, STAGE(Bw, col0 + 0,   col0 + 64,  B0B + 0,     B0B + 8192,  kt2));
    PHASE(2, A0B, false, B0B, false, STAGE(Bw, col0 + 128, col0 + 192, B0B + 16384, B0B + 24576, kt2));
    PHASE(3, A0B, false, B0B, true,  STAGE(A,  row0 + 0,   row0 + 128, A0B + 0,     A0B + 16384, kt2));
    PHASE(0, A1B, true,  B1B, false, STAGE(A,  row0 + 64,  row0 + 192, A0B + 8192,  A0B + 24576, kt2));
    PHASE(1, A1B, false, B1B, false, STAGE(Bw, col0 + 0,   col0 + 64,  B1B + 0,     B1B + 8192,  kt3));
    PHASE(2, A1B, false, B1B, false, STAGE(Bw, col0 + 128, col0 + 192, B1B + 16384, B1B + 24576, kt3));
    PHASE(3, A1B, false, B1B, true,  STAGE(A,  row0 + 0,   row0 + 128, A1B + 0,     A1B + 16384, kt3));
  }

  // ---- epilogue: bias + relu + bf16 store ----
#pragma unroll
  for (int m = 0; m < 8; ++m) {
    int gr0 = row0 + wr * 128 + m * 16 + kh * 4;
#pragma unroll
    for (int n = 0; n < 4; ++n) {
      int gc = col0 + wc * 64 + n * 16 + lr;
      float bv = bias[gc];
#pragma unroll
      for (int v = 0; v < 4; ++v) {
        float val = fmaxf(acc[m][n][v] + bv, 0.f);
        Cout[(size_t)(gr0 + v) * 2048 + gc] = f2b(val);
      }
    }
  }
}

// ---------------- skinny GEMM3 + tanh: [16384,2048]x[32,2048]^T -> d_out ----------------
__global__ __launch_bounds__(128) void gemm_skinny(
    const unsigned short* __restrict__ A,    // h2 [16384,2048] bf16
    const unsigned short* __restrict__ Bw,   // Weff [32,2048] bf16
    const float* __restrict__ beff,          // [32]
    float* __restrict__ out) {               // [16384,32] fp32
  const int t = threadIdx.x, lane = t & 63, w = t >> 6;
  const int lr = lane & 15, kh = lane >> 4;
  const int row0 = blockIdx.x * 64 + w * 32;
  f32x4 acc[2][2];
#pragma unroll
  for (int m = 0; m < 2; ++m)
#pragma unroll
    for (int n = 0; n < 2; ++n) acc[m][n] = (f32x4){0.f, 0.f, 0.f, 0.f};

#pragma unroll 4
  for (int kt = 0; kt < HID; kt += 32) {
    bf16x8 af[2], bv[2];
#pragma unroll
    for (int m = 0; m < 2; ++m)
      af[m] = *reinterpret_cast<const bf16x8*>(A + (size_t)(row0 + m * 16 + lr) * HID + kt + kh * 8);
#pragma unroll
    for (int n = 0; n < 2; ++n)
      bv[n] = *reinterpret_cast<const bf16x8*>(Bw + (size_t)(n * 16 + lr) * HID + kt + kh * 8);
#pragma unroll
    for (int m = 0; m < 2; ++m)
#pragma unroll
      for (int n = 0; n < 2; ++n)
        acc[m][n] = __builtin_amdgcn_mfma_f32_16x16x32_bf16(af[m], bv[n], acc[m][n], 0, 0, 0);
  }
#pragma unroll
  for (int m = 0; m < 2; ++m)
#pragma unroll
    for (int n = 0; n < 2; ++n)
#pragma unroll
      for (int v = 0; v < 4; ++v) {
        int row = row0 + m * 16 + kh * 4 + v;
        int col = n * 16 + lr;
        out[(size_t)row * ADIM + col] = tanhf(acc[m][n][v] + beff[col]);
      }
}

// ---------------- launch ----------------
extern "C" void kernel_launch(void* const* d_in, const int* in_sizes, int n_in,
                              void* d_out, int out_size, void* d_ws, size_t ws_size,
                              hipStream_t stream) {
  const float* state    = (const float*)d_in[0];
  const float* mean_enc = (const float*)d_in[1];
  const float* std_enc  = (const float*)d_in[2];
  const float* W1 = (const float*)d_in[3];
  const float* b1 = (const float*)d_in[4];
  const float* W2 = (const float*)d_in[5];
  const float* b2 = (const float*)d_in[6];
  const float* W3 = (const float*)d_in[7];
  const float* b3 = (const float*)d_in[8];
  const float* Wd = (const float*)d_in[9];
  const float* bd = (const float*)d_in[10];

  char* ws = (char*)d_ws;
  unsigned short* W1b   = (unsigned short*)(ws + 0);           //  5,242,880
  unsigned short* W2b   = (unsigned short*)(ws + 5242880);     //  8,388,608
  unsigned short* Weff  = (unsigned short*)(ws + 13631488);    //    131,072
  float*          beff  = (float*)(ws + 13762560);             //        128
  unsigned short* spine = (unsigned short*)(ws + 13762688);    // 41,943,040
  unsigned short* h1    = (unsigned short*)(ws + 55705728);    // 67,108,864
  unsigned short* h2    = (unsigned short*)(ws + 122814592);   // 67,108,864 -> end ~190MB

  // weight preprocessing
  f2b_kernel<<<5120, 256, 0, stream>>>(W1, (unsigned*)W1b, 1310720);
  f2b_kernel<<<8192, 256, 0, stream>>>(W2, (unsigned*)W2b, 2097152);
  weff_kernel<<<256, 256, 0, stream>>>(W3, Wd, Weff);
  beff_kernel<<<1, 64, 0, stream>>>(b3, Wd, bd, beff);

  // encoder
  encoder_kernel<<<(BATCH * SDIM) / 256, 256, 0, stream>>>(state, mean_enc, std_enc, (unsigned*)spine);

  // GEMM chain
  gemm256<<<512, 512, 0, stream>>>(spine, W1b, b1, h1, KSPINE, KSPINE / 128);
  gemm256<<<512, 512, 0, stream>>>(h1,    W2b, b2, h2, HID,    HID / 128);
  gemm_skinny<<<BATCH / 64, 128, 0, stream>>>(h2, Weff, beff, (float*)d_out);
}

// Round 3
// 257.006 us; speedup vs baseline: 1.3005x; 1.0496x over previous
//
#include <hip/hip_runtime.h>
#include <hip/hip_bf16.h>
#include <stdint.h>

// ---------------- problem constants ----------------
#define BATCH   16384
#define SDIM    128
#define ENCK    10
#define ADIM    32
#define DECK    10
#define HID     2048
#define KSPINE  1280      // SDIM*ENCK

typedef __bf16 bf16x8 __attribute__((ext_vector_type(8)));
typedef float  f32x4  __attribute__((ext_vector_type(4)));

typedef __attribute__((address_space(1))) const void kGlobalVoid;
typedef __attribute__((address_space(3))) void       kLdsVoid;

__device__ __forceinline__ unsigned short f2b(float f) {
  union { float f; unsigned u; } v; v.f = f;
  unsigned r = v.u + 0x7fffu + ((v.u >> 16) & 1u);   // RNE
  return (unsigned short)(r >> 16);
}

// ---------------- fp32 -> bf16 convert (2 elems/thread) ----------------
__global__ void f2b_kernel(const float* __restrict__ in, unsigned* __restrict__ out, int n2) {
  int i = blockIdx.x * blockDim.x + threadIdx.x;
  if (i >= n2) return;
  float2 v = reinterpret_cast<const float2*>(in)[i];
  out[i] = (unsigned)f2b(v.x) | ((unsigned)f2b(v.y) << 16);
}

// ---------------- encoder: sigmoid((x-mean)/std) -> bf16 spine ----------------
__global__ void encoder_kernel(const float* __restrict__ state,
                               const float* __restrict__ mean,
                               const float* __restrict__ stdv,
                               unsigned* __restrict__ spine) {
  int idx = blockIdx.x * blockDim.x + threadIdx.x;   // b*SDIM + d
  if (idx >= BATCH * SDIM) return;
  int d = idx & (SDIM - 1);
  float x = state[idx];
  float vals[ENCK];
#pragma unroll
  for (int k = 0; k < ENCK; ++k) {
    float z = (x - mean[d * ENCK + k]) / stdv[d * ENCK + k];
    vals[k] = 1.f / (1.f + __expf(-z));
  }
  unsigned* dst = spine + idx * (ENCK / 2);
#pragma unroll
  for (int k = 0; k < ENCK / 2; ++k)
    dst[k] = (unsigned)f2b(vals[2 * k]) | ((unsigned)f2b(vals[2 * k + 1]) << 16);
}

// ---------------- Weff/beff builders: fold grouped-conv into W3 ----------------
__global__ void weff_kernel(const float* __restrict__ W3, const float* __restrict__ Wd,
                            unsigned short* __restrict__ Weff) {
  int idx = blockIdx.x * 256 + threadIdx.x;   // a*2048 + j, 65536 total
  int a = idx >> 11, j = idx & 2047;
  float s = 0.f;
#pragma unroll
  for (int k = 0; k < DECK; ++k)
    s += Wd[a * DECK + k] * W3[(size_t)(a * DECK + k) * HID + j];
  Weff[idx] = f2b(s);
}

__global__ void beff_kernel(const float* __restrict__ b3, const float* __restrict__ Wd,
                            const float* __restrict__ bd, float* __restrict__ beff) {
  int a = threadIdx.x;
  if (a >= ADIM) return;
  float s = bd[a];
#pragma unroll
  for (int k = 0; k < DECK; ++k) s += Wd[a * DECK + k] * b3[a * DECK + k];
  beff[a] = s;
}

// ---------------- 256x256 8-phase bf16 GEMM (T2+T3+T4+T5) ----------------
// C[M,2048] = relu(A[M,K] * Bw[2048,K]^T + bias), bf16 out.
// 512 thr = 8 waves (2M x 4N); per-wave 128x64 out = acc[8][4] f32x4.
// LDS 128 KiB: buf{0,1} x (A 32K + B 32K), rows of 64 bf16 (128B), XOR-swizzled.
// Phase p computes m-pair (p&3) over all 4 n-frags x 2 kslices = 16 MFMA.
// B fragments reg-cached at P1/P5 (so B-LDS is restageable from P2/P6 on).
// Stage order per iter: P1:buf1.Aq2q3<-t1 | P2,P3:buf0.B<-t2 | P4:buf0.Aq0q1<-t2
//                       P5:buf0.Aq2q3<-t2 | P6,P7:buf1.B<-t3 | P8:buf1.Aq0q1<-t3
// vmcnt(6) before closing barrier of P4 and P8 (retire all but 3 newest stages).
// R2 change: XCD mapping = M-band per XCD (A fetched once per chip; B shared
// by 4 co-resident M-blocks per XCD) instead of N-panel per XCD (A refetched x8).

#define A0B 0
#define B0B 32768
#define A1B 65536
#define B1B 98304

#define FENCE asm volatile("" ::: "memory")

#define STAGE(BASEPTR, R0A, R0B, LDS0, LDS1, KT)                                             \
  __builtin_amdgcn_global_load_lds((kGlobalVoid*)((BASEPTR) + (size_t)((R0A) + rs) * K + (KT) + ce), \
                                   (kLdsVoid*)(smem + (LDS0) + t * 16), 16, 0, 0);           \
  __builtin_amdgcn_global_load_lds((kGlobalVoid*)((BASEPTR) + (size_t)((R0B) + rs) * K + (KT) + ce), \
                                   (kLdsVoid*)(smem + (LDS1) + t * 16), 16, 0, 0);

#define PHASE(mp, ABASE, DOB, BBASE, DOVM, STAGES)                                           \
  do {                                                                                       \
    bf16x8 af[2][2];                                                                         \
    _Pragma("unroll")                                                                        \
    for (int j = 0; j < 2; ++j) {                                                            \
      _Pragma("unroll")                                                                      \
      for (int ks = 0; ks < 2; ++ks) {                                                       \
        int rowl = wr * 128 + ((mp) * 2 + j) * 16 + lr;                                      \
        af[j][ks] = *reinterpret_cast<const bf16x8*>(                                        \
            smem + (ABASE) + rowl * 128 + ((((ks) << 6) | (kh << 4)) ^ swz));                \
      }                                                                                      \
    }                                                                                        \
    if (DOB) {                                                                               \
      _Pragma("unroll")                                                                      \
      for (int n = 0; n < 4; ++n) {                                                          \
        _Pragma("unroll")                                                                    \
        for (int ks = 0; ks < 2; ++ks) {                                                     \
          int rowl = wc * 64 + n * 16 + lr;                                                  \
          bfv[n][ks] = *reinterpret_cast<const bf16x8*>(                                     \
              smem + (BBASE) + rowl * 128 + ((((ks) << 6) | (kh << 4)) ^ swz));              \
        }                                                                                    \
      }                                                                                      \
    }                                                                                        \
    STAGES                                                                                   \
    FENCE;                                                                                   \
    __builtin_amdgcn_s_barrier();                                                            \
    asm volatile("s_waitcnt lgkmcnt(0)" ::: "memory");                                       \
    __builtin_amdgcn_sched_barrier(0);                                                       \
    __builtin_amdgcn_s_setprio(1);                                                           \
    _Pragma("unroll")                                                                        \
    for (int j = 0; j < 2; ++j)                                                              \
      _Pragma("unroll")                                                                      \
      for (int n = 0; n < 4; ++n)                                                            \
        _Pragma("unroll")                                                                    \
        for (int ks = 0; ks < 2; ++ks)                                                       \
          acc[(mp) * 2 + j][n] =                                                             \
              __builtin_amdgcn_mfma_f32_16x16x32_bf16(af[j][ks], bfv[n][ks],                 \
                                                      acc[(mp) * 2 + j][n], 0, 0, 0);        \
    __builtin_amdgcn_s_setprio(0);                                                           \
    if (DOVM) asm volatile("s_waitcnt vmcnt(6)" ::: "memory");                               \
    FENCE;                                                                                   \
    __builtin_amdgcn_s_barrier();                                                            \
  } while (0)

__global__ __launch_bounds__(512, 2) void gemm256(
    const unsigned short* __restrict__ A,    // [M,K] bf16
    const unsigned short* __restrict__ Bw,   // [2048,K] bf16
    const float* __restrict__ bias,          // [2048]
    unsigned short* __restrict__ Cout,       // [M,2048] bf16
    int K, int NI) {                         // NI = K/128
  __shared__ char smem[131072];

  const int t    = threadIdx.x;
  const int lane = t & 63;
  const int w    = t >> 6;
  const int wr   = w >> 2;      // 0..1
  const int wc   = w & 3;       // 0..3
  const int lr   = lane & 15;
  const int kh   = lane >> 4;   // 0..3
  const int swz  = (lr & 7) << 4;
  const int rs   = t >> 3;                      // stage row within 64-row band
  const int ce   = ((t & 7) ^ (rs & 7)) << 3;   // inverse-swizzled col (elements)

  // XCD-aware mapping: XCD x owns M-band (8 M-blocks) x all 8 N-blocks.
  // Concurrent round per XCD = 4 M x 8 N -> A slice shared x8, B slice x4.
  const int bid = blockIdx.x;
  const int xcd = bid & 7, idx = bid >> 3;           // idx in [0,64)
  const int row0 = (xcd * 8 + (idx >> 3)) * 256;
  const int col0 = (idx & 7) * 256;

  f32x4 acc[8][4];
#pragma unroll
  for (int m = 0; m < 8; ++m)
#pragma unroll
    for (int n = 0; n < 4; ++n)
      acc[m][n] = (f32x4){0.f, 0.f, 0.f, 0.f};

  bf16x8 bfv[4][2];

  // ---- prologue: buf0 <- tile0 (4 stages), buf1 <- tile1 B + Aq0q1 (3 stages) ----
  STAGE(Bw, col0 + 0,   col0 + 64,  B0B + 0,     B0B + 8192,  0);
  STAGE(Bw, col0 + 128, col0 + 192, B0B + 16384, B0B + 24576, 0);
  STAGE(A,  row0 + 0,   row0 + 128, A0B + 0,     A0B + 16384, 0);
  STAGE(A,  row0 + 64,  row0 + 192, A0B + 8192,  A0B + 24576, 0);
  STAGE(Bw, col0 + 0,   col0 + 64,  B1B + 0,     B1B + 8192,  64);
  STAGE(Bw, col0 + 128, col0 + 192, B1B + 16384, B1B + 24576, 64);
  STAGE(A,  row0 + 0,   row0 + 128, A1B + 0,     A1B + 16384, 64);
  asm volatile("s_waitcnt vmcnt(6)" ::: "memory");
  FENCE;
  __builtin_amdgcn_s_barrier();

  for (int i = 0; i < NI; ++i) {
    int kt0 = i << 7;
    int kt1 = kt0 + 64;
    int kt2 = kt0 + 128; if (kt2 >= K) kt2 -= K;   // wrapped prefetch on last iter (unused)
    int kt3 = kt0 + 192; if (kt3 >= K) kt3 -= K;

    PHASE(0, A0B, true,  B0B, false, STAGE(A,  row0 + 64,  row0 + 192, A1B + 8192,  A1B + 24576, kt1));
    PHASE(1, A0B, false, B0B, false, STAGE(Bw, col0 + 0,   col0 + 64,  B0B + 0,     B0B + 8192,  kt2));
    PHASE(2, A0B, false, B0B, false, STAGE(Bw, col0 + 128, col0 + 192, B0B + 16384, B0B + 24576, kt2));
    PHASE(3, A0B, false, B0B, true,  STAGE(A,  row0 + 0,   row0 + 128, A0B + 0,     A0B + 16384, kt2));
    PHASE(0, A1B, true,  B1B, false, STAGE(A,  row0 + 64,  row0 + 192, A0B + 8192,  A0B + 24576, kt2));
    PHASE(1, A1B, false, B1B, false, STAGE(Bw, col0 + 0,   col0 + 64,  B1B + 0,     B1B + 8192,  kt3));
    PHASE(2, A1B, false, B1B, false, STAGE(Bw, col0 + 128, col0 + 192, B1B + 16384, B1B + 24576, kt3));
    PHASE(3, A1B, false, B1B, true,  STAGE(A,  row0 + 0,   row0 + 128, A1B + 0,     A1B + 16384, kt3));
  }

  // ---- epilogue: bias + relu + bf16 store ----
#pragma unroll
  for (int m = 0; m < 8; ++m) {
    int gr0 = row0 + wr * 128 + m * 16 + kh * 4;
#pragma unroll
    for (int n = 0; n < 4; ++n) {
      int gc = col0 + wc * 64 + n * 16 + lr;
      float bv = bias[gc];
#pragma unroll
      for (int v = 0; v < 4; ++v) {
        float val = fmaxf(acc[m][n][v] + bv, 0.f);
        Cout[(size_t)(gr0 + v) * 2048 + gc] = f2b(val);
      }
    }
  }
}

// ---------------- skinny GEMM3 + tanh: [16384,2048]x[32,2048]^T -> d_out ----------------
__global__ __launch_bounds__(128) void gemm_skinny(
    const unsigned short* __restrict__ A,    // h2 [16384,2048] bf16
    const unsigned short* __restrict__ Bw,   // Weff [32,2048] bf16
    const float* __restrict__ beff,          // [32]
    float* __restrict__ out) {               // [16384,32] fp32
  const int t = threadIdx.x, lane = t & 63, w = t >> 6;
  const int lr = lane & 15, kh = lane >> 4;
  const int row0 = blockIdx.x * 64 + w * 32;
  f32x4 acc[2][2];
#pragma unroll
  for (int m = 0; m < 2; ++m)
#pragma unroll
    for (int n = 0; n < 2; ++n) acc[m][n] = (f32x4){0.f, 0.f, 0.f, 0.f};

#pragma unroll 4
  for (int kt = 0; kt < HID; kt += 32) {
    bf16x8 af[2], bv[2];
#pragma unroll
    for (int m = 0; m < 2; ++m)
      af[m] = *reinterpret_cast<const bf16x8*>(A + (size_t)(row0 + m * 16 + lr) * HID + kt + kh * 8);
#pragma unroll
    for (int n = 0; n < 2; ++n)
      bv[n] = *reinterpret_cast<const bf16x8*>(Bw + (size_t)(n * 16 + lr) * HID + kt + kh * 8);
#pragma unroll
    for (int m = 0; m < 2; ++m)
#pragma unroll
      for (int n = 0; n < 2; ++n)
        acc[m][n] = __builtin_amdgcn_mfma_f32_16x16x32_bf16(af[m], bv[n], acc[m][n], 0, 0, 0);
  }
#pragma unroll
  for (int m = 0; m < 2; ++m)
#pragma unroll
    for (int n = 0; n < 2; ++n)
#pragma unroll
      for (int v = 0; v < 4; ++v) {
        int row = row0 + m * 16 + kh * 4 + v;
        int col = n * 16 + lr;
        out[(size_t)row * ADIM + col] = tanhf(acc[m][n][v] + beff[col]);
      }
}

// ---------------- launch ----------------
extern "C" void kernel_launch(void* const* d_in, const int* in_sizes, int n_in,
                              void* d_out, int out_size, void* d_ws, size_t ws_size,
                              hipStream_t stream) {
  const float* state    = (const float*)d_in[0];
  const float* mean_enc = (const float*)d_in[1];
  const float* std_enc  = (const float*)d_in[2];
  const float* W1 = (const float*)d_in[3];
  const float* b1 = (const float*)d_in[4];
  const float* W2 = (const float*)d_in[5];
  const float* b2 = (const float*)d_in[6];
  const float* W3 = (const float*)d_in[7];
  const float* b3 = (const float*)d_in[8];
  const float* Wd = (const float*)d_in[9];
  const float* bd = (const float*)d_in[10];

  char* ws = (char*)d_ws;
  unsigned short* W1b   = (unsigned short*)(ws + 0);           //  5,242,880
  unsigned short* W2b   = (unsigned short*)(ws + 5242880);     //  8,388,608
  unsigned short* Weff  = (unsigned short*)(ws + 13631488);    //    131,072
  float*          beff  = (float*)(ws + 13762560);             //        128
  unsigned short* spine = (unsigned short*)(ws + 13762688);    // 41,943,040
  unsigned short* h1    = (unsigned short*)(ws + 55705728);    // 67,108,864
  unsigned short* h2    = (unsigned short*)(ws + 122814592);   // 67,108,864 -> end ~190MB

  // weight preprocessing
  f2b_kernel<<<5120, 256, 0, stream>>>(W1, (unsigned*)W1b, 1310720);
  f2b_kernel<<<8192, 256, 0, stream>>>(W2, (unsigned*)W2b, 2097152);
  weff_kernel<<<256, 256, 0, stream>>>(W3, Wd, Weff);
  beff_kernel<<<1, 64, 0, stream>>>(b3, Wd, bd, beff);

  // encoder
  encoder_kernel<<<(BATCH * SDIM) / 256, 256, 0, stream>>>(state, mean_enc, std_enc, (unsigned*)spine);

  // GEMM chain
  gemm256<<<512, 512, 0, stream>>>(spine, W1b, b1, h1, KSPINE, KSPINE / 128);
  gemm256<<<512, 512, 0, stream>>>(h1,    W2b, b2, h2, HID,    HID / 128);
  gemm_skinny<<<BATCH / 64, 128, 0, stream>>>(h2, Weff, beff, (float*)d_out);
}

// Round 4
// 249.263 us; speedup vs baseline: 1.3409x; 1.0311x over previous
//
#include <hip/hip_runtime.h>
#include <hip/hip_bf16.h>
#include <stdint.h>

// ---------------- problem constants ----------------
#define BATCH   16384
#define SDIM    128
#define ENCK    10
#define ADIM    32
#define DECK    10
#define HID     2048
#define KSPINE  1280      // SDIM*ENCK

typedef __bf16 bf16x8 __attribute__((ext_vector_type(8)));
typedef float  f32x4  __attribute__((ext_vector_type(4)));

typedef __attribute__((address_space(1))) const void kGlobalVoid;
typedef __attribute__((address_space(3))) void       kLdsVoid;

__device__ __forceinline__ unsigned short f2b(float f) {
  union { float f; unsigned u; } v; v.f = f;
  unsigned r = v.u + 0x7fffu + ((v.u >> 16) & 1u);   // RNE
  return (unsigned short)(r >> 16);
}

// ---------------- fp32 -> bf16 convert (2 elems/thread) ----------------
__global__ void f2b_kernel(const float* __restrict__ in, unsigned* __restrict__ out, int n2) {
  int i = blockIdx.x * blockDim.x + threadIdx.x;
  if (i >= n2) return;
  float2 v = reinterpret_cast<const float2*>(in)[i];
  out[i] = (unsigned)f2b(v.x) | ((unsigned)f2b(v.y) << 16);
}

// ---------------- encoder: sigmoid((x-mean)/std) -> bf16 spine ----------------
__global__ void encoder_kernel(const float* __restrict__ state,
                               const float* __restrict__ mean,
                               const float* __restrict__ stdv,
                               unsigned* __restrict__ spine) {
  int idx = blockIdx.x * blockDim.x + threadIdx.x;   // b*SDIM + d
  if (idx >= BATCH * SDIM) return;
  int d = idx & (SDIM - 1);
  float x = state[idx];
  float vals[ENCK];
#pragma unroll
  for (int k = 0; k < ENCK; ++k) {
    float z = (x - mean[d * ENCK + k]) / stdv[d * ENCK + k];
    vals[k] = 1.f / (1.f + __expf(-z));
  }
  unsigned* dst = spine + idx * (ENCK / 2);
#pragma unroll
  for (int k = 0; k < ENCK / 2; ++k)
    dst[k] = (unsigned)f2b(vals[2 * k]) | ((unsigned)f2b(vals[2 * k + 1]) << 16);
}

// ---------------- Weff/beff builders: fold grouped-conv into W3 ----------------
__global__ void weff_kernel(const float* __restrict__ W3, const float* __restrict__ Wd,
                            unsigned short* __restrict__ Weff) {
  int idx = blockIdx.x * 256 + threadIdx.x;   // a*2048 + j, 65536 total
  int a = idx >> 11, j = idx & 2047;
  float s = 0.f;
#pragma unroll
  for (int k = 0; k < DECK; ++k)
    s += Wd[a * DECK + k] * W3[(size_t)(a * DECK + k) * HID + j];
  Weff[idx] = f2b(s);
}

__global__ void beff_kernel(const float* __restrict__ b3, const float* __restrict__ Wd,
                            const float* __restrict__ bd, float* __restrict__ beff) {
  int a = threadIdx.x;
  if (a >= ADIM) return;
  float s = bd[a];
#pragma unroll
  for (int k = 0; k < DECK; ++k) s += Wd[a * DECK + k] * b3[a * DECK + k];
  beff[a] = s;
}

// ---------------- 256x256 8-phase bf16 GEMM, shadow-pipelined LDS reads ----------------
// Phase body: {lgkm(0) [waits prev phase's shadow reads] ; [vmcnt(6) @p3,p7] ;
//              16 MFMA on prefetched regs ; shadow ds_reads for phase+1 ;
//              stage global_load_lds ; barrier}  -- ONE barrier per phase.
// Register double-buffers: af0/af1 (A frags, parity by phase), bfv0/bfv1 (B frags, by K-half).
// Stage schedule (iter i, kt0=i*128): p0:A1 q1q3<-kt1 | p1,p2:B0<-kt2 | p3:A0 q0q2<-kt2
//   p4:A0 q1q3<-kt2 | p5,p6:B1<-kt3 | p7:A1 q0q2<-kt3.
// Deadlines: every region is staged >=4 phases before first read; vmcnt(6) at p3 retires
// {p4',p5',p6',p7'}, at p7 retires {p0..p3} -- always before the shadow read that needs them.

#define A0B 0
#define B0B 32768
#define A1B 65536
#define B1B 98304

#define FENCE asm volatile("" ::: "memory")

#define STAGE(BASEPTR, R0A, R0B, LDS0, LDS1, KT)                                             \
  __builtin_amdgcn_global_load_lds((kGlobalVoid*)((BASEPTR) + (size_t)((R0A) + rs) * K + (KT) + ce), \
                                   (kLdsVoid*)(smem + (LDS0) + t * 16), 16, 0, 0);           \
  __builtin_amdgcn_global_load_lds((kGlobalVoid*)((BASEPTR) + (size_t)((R0B) + rs) * K + (KT) + ce), \
                                   (kLdsVoid*)(smem + (LDS1) + t * 16), 16, 0, 0);

#define DS_AF(DST, ABASE, MPN)                                                               \
  _Pragma("unroll")                                                                          \
  for (int j2 = 0; j2 < 2; ++j2) {                                                           \
    _Pragma("unroll")                                                                        \
    for (int ks = 0; ks < 2; ++ks) {                                                         \
      int rowl = wr * 128 + (MPN) * 32 + j2 * 16 + lr;                                       \
      DST[j2][ks] = *reinterpret_cast<const bf16x8*>(                                        \
          smem + (ABASE) + rowl * 128 + ((((ks) << 6) | (kh << 4)) ^ swz));                  \
    }                                                                                        \
  }

#define DS_BF(DST, BBASE)                                                                    \
  _Pragma("unroll")                                                                          \
  for (int n = 0; n < 4; ++n) {                                                              \
    _Pragma("unroll")                                                                        \
    for (int ks = 0; ks < 2; ++ks) {                                                         \
      int rowl = wc * 64 + n * 16 + lr;                                                      \
      DST[n][ks] = *reinterpret_cast<const bf16x8*>(                                         \
          smem + (BBASE) + rowl * 128 + ((((ks) << 6) | (kh << 4)) ^ swz));                  \
    }                                                                                        \
  }

#define MFMA16(MP, AF, BF)                                                                   \
  _Pragma("unroll")                                                                          \
  for (int j2 = 0; j2 < 2; ++j2)                                                             \
    _Pragma("unroll")                                                                        \
    for (int n = 0; n < 4; ++n)                                                              \
      _Pragma("unroll")                                                                      \
      for (int ks = 0; ks < 2; ++ks)                                                         \
        acc[(MP) * 2 + j2][n] = __builtin_amdgcn_mfma_f32_16x16x32_bf16(                     \
            AF[j2][ks], BF[n][ks], acc[(MP) * 2 + j2][n], 0, 0, 0);

#define PH(MP, AF_CUR, AF_NXT, BF_CUR, NXT_ABASE, NXT_MP, DOVM, DOB, NXT_BF, NXT_BBASE, STG) \
  do {                                                                                       \
    asm volatile("s_waitcnt lgkmcnt(0)" ::: "memory");                                       \
    __builtin_amdgcn_sched_barrier(0);                                                       \
    if (DOVM) {                                                                              \
      asm volatile("s_waitcnt vmcnt(6)" ::: "memory");                                       \
      __builtin_amdgcn_sched_barrier(0);                                                     \
    }                                                                                        \
    __builtin_amdgcn_s_setprio(1);                                                           \
    MFMA16(MP, AF_CUR, BF_CUR);                                                              \
    __builtin_amdgcn_s_setprio(0);                                                           \
    DS_AF(AF_NXT, NXT_ABASE, NXT_MP);                                                        \
    if (DOB) { DS_BF(NXT_BF, NXT_BBASE); }                                                   \
    STG;                                                                                     \
    FENCE;                                                                                   \
    __builtin_amdgcn_s_barrier();                                                            \
  } while (0)

__global__ __launch_bounds__(512, 2) void gemm256(
    const unsigned short* __restrict__ A,    // [M,K] bf16
    const unsigned short* __restrict__ Bw,   // [2048,K] bf16
    const float* __restrict__ bias,          // [2048]
    unsigned short* __restrict__ Cout,       // [M,2048] bf16
    int K, int NI) {                         // NI = K/128
  __shared__ char smem[131072];

  const int t    = threadIdx.x;
  const int lane = t & 63;
  const int w    = t >> 6;
  const int wr   = w >> 2;      // 0..1
  const int wc   = w & 3;       // 0..3
  const int lr   = lane & 15;
  const int kh   = lane >> 4;   // 0..3
  const int swz  = (lr & 7) << 4;
  const int rs   = t >> 3;                      // stage row within 64-row band
  const int ce   = ((t & 7) ^ (rs & 7)) << 3;   // inverse-swizzled col (elements)

  // XCD-aware mapping: XCD owns an M-band x all 8 N-blocks (A fetched once per chip).
  const int bid = blockIdx.x;
  const int xcd = bid & 7, idx = bid >> 3;           // idx in [0,64)
  const int row0 = (xcd * 8 + (idx >> 3)) * 256;
  const int col0 = (idx & 7) * 256;

  f32x4 acc[8][4];
#pragma unroll
  for (int m = 0; m < 8; ++m)
#pragma unroll
    for (int n = 0; n < 4; ++n)
      acc[m][n] = (f32x4){0.f, 0.f, 0.f, 0.f};

  bf16x8 af0[2][2], af1[2][2], bfv0[4][2], bfv1[4][2];

  // ---- prologue: buf0 full <- kt0, buf1 B + A q0q2 <- kt1 (7 stage-pairs) ----
  STAGE(Bw, col0 + 0,   col0 + 64,  B0B + 0,     B0B + 8192,  0);
  STAGE(Bw, col0 + 128, col0 + 192, B0B + 16384, B0B + 24576, 0);
  STAGE(A,  row0 + 0,   row0 + 128, A0B + 0,     A0B + 16384, 0);
  STAGE(A,  row0 + 64,  row0 + 192, A0B + 8192,  A0B + 24576, 0);
  STAGE(Bw, col0 + 0,   col0 + 64,  B1B + 0,     B1B + 8192,  64);
  STAGE(Bw, col0 + 128, col0 + 192, B1B + 16384, B1B + 24576, 64);
  STAGE(A,  row0 + 0,   row0 + 128, A1B + 0,     A1B + 16384, 64);
  asm volatile("s_waitcnt vmcnt(6)" ::: "memory");   // retire the 4 buf0 stage-pairs
  FENCE;
  __builtin_amdgcn_s_barrier();
  // initial prefetch for phase 0
  DS_AF(af0, A0B, 0);
  DS_BF(bfv0, B0B);

  for (int i = 0; i < NI; ++i) {
    int kt0 = i << 7;
    int kt1 = kt0 + 64;
    int kt2 = kt0 + 128; if (kt2 >= K) kt2 -= K;   // wrapped on last iter (data unused)
    int kt3 = kt0 + 192; if (kt3 >= K) kt3 -= K;

    PH(0, af0, af1, bfv0, A0B, 1, false, false, bfv1, B1B,
       STAGE(A,  row0 + 64,  row0 + 192, A1B + 8192,  A1B + 24576, kt1));
    PH(1, af1, af0, bfv0, A0B, 2, false, false, bfv1, B1B,
       STAGE(Bw, col0 + 0,   col0 + 64,  B0B + 0,     B0B + 8192,  kt2));
    PH(2, af0, af1, bfv0, A0B, 3, false, false, bfv1, B1B,
       STAGE(Bw, col0 + 128, col0 + 192, B0B + 16384, B0B + 24576, kt2));
    PH(3, af1, af0, bfv0, A1B, 0, true,  true,  bfv1, B1B,
       STAGE(A,  row0 + 0,   row0 + 128, A0B + 0,     A0B + 16384, kt2));
    PH(0, af0, af1, bfv1, A1B, 1, false, false, bfv0, B0B,
       STAGE(A,  row0 + 64,  row0 + 192, A0B + 8192,  A0B + 24576, kt2));
    PH(1, af1, af0, bfv1, A1B, 2, false, false, bfv0, B0B,
       STAGE(Bw, col0 + 0,   col0 + 64,  B1B + 0,     B1B + 8192,  kt3));
    PH(2, af0, af1, bfv1, A1B, 3, false, false, bfv0, B0B,
       STAGE(Bw, col0 + 128, col0 + 192, B1B + 16384, B1B + 24576, kt3));
    PH(3, af1, af0, bfv1, A0B, 0, true,  true,  bfv0, B0B,
       STAGE(A,  row0 + 0,   row0 + 128, A1B + 0,     A1B + 16384, kt3));
  }

  // ---- epilogue: bias + relu + bf16 store ----
#pragma unroll
  for (int m = 0; m < 8; ++m) {
    int gr0 = row0 + wr * 128 + m * 16 + kh * 4;
#pragma unroll
    for (int n = 0; n < 4; ++n) {
      int gc = col0 + wc * 64 + n * 16 + lr;
      float bv = bias[gc];
#pragma unroll
      for (int v = 0; v < 4; ++v) {
        float val = fmaxf(acc[m][n][v] + bv, 0.f);
        Cout[(size_t)(gr0 + v) * 2048 + gc] = f2b(val);
      }
    }
  }
}

// ---------------- skinny GEMM3 + tanh: [16384,2048]x[32,2048]^T -> d_out ----------------
// 16 rows/wave, 1024 waves (512 blocks x 2 waves) for latency tolerance; HBM-bound.
__global__ __launch_bounds__(128) void gemm_skinny(
    const unsigned short* __restrict__ A,    // h2 [16384,2048] bf16
    const unsigned short* __restrict__ Bw,   // Weff [32,2048] bf16
    const float* __restrict__ beff,          // [32]
    float* __restrict__ out) {               // [16384,32] fp32
  const int t = threadIdx.x, lane = t & 63, w = t >> 6;
  const int lr = lane & 15, kh = lane >> 4;
  const int row0 = (blockIdx.x * 2 + w) * 16;
  f32x4 acc[2];
  acc[0] = (f32x4){0.f, 0.f, 0.f, 0.f};
  acc[1] = (f32x4){0.f, 0.f, 0.f, 0.f};

  const unsigned short* Arow = A  + (size_t)(row0 + lr) * HID + kh * 8;
  const unsigned short* B0   = Bw + (size_t)(lr) * HID + kh * 8;
  const unsigned short* B1   = Bw + (size_t)(16 + lr) * HID + kh * 8;

#pragma unroll 4
  for (int kt = 0; kt < HID; kt += 32) {
    bf16x8 a  = *reinterpret_cast<const bf16x8*>(Arow + kt);
    bf16x8 b0 = *reinterpret_cast<const bf16x8*>(B0 + kt);
    bf16x8 b1 = *reinterpret_cast<const bf16x8*>(B1 + kt);
    acc[0] = __builtin_amdgcn_mfma_f32_16x16x32_bf16(a, b0, acc[0], 0, 0, 0);
    acc[1] = __builtin_amdgcn_mfma_f32_16x16x32_bf16(a, b1, acc[1], 0, 0, 0);
  }
#pragma unroll
  for (int n = 0; n < 2; ++n)
#pragma unroll
    for (int v = 0; v < 4; ++v) {
      int row = row0 + kh * 4 + v;
      int col = n * 16 + lr;
      out[(size_t)row * ADIM + col] = tanhf(acc[n][v] + beff[col]);
    }
}

// ---------------- launch ----------------
extern "C" void kernel_launch(void* const* d_in, const int* in_sizes, int n_in,
                              void* d_out, int out_size, void* d_ws, size_t ws_size,
                              hipStream_t stream) {
  const float* state    = (const float*)d_in[0];
  const float* mean_enc = (const float*)d_in[1];
  const float* std_enc  = (const float*)d_in[2];
  const float* W1 = (const float*)d_in[3];
  const float* b1 = (const float*)d_in[4];
  const float* W2 = (const float*)d_in[5];
  const float* b2 = (const float*)d_in[6];
  const float* W3 = (const float*)d_in[7];
  const float* b3 = (const float*)d_in[8];
  const float* Wd = (const float*)d_in[9];
  const float* bd = (const float*)d_in[10];

  char* ws = (char*)d_ws;
  unsigned short* W1b   = (unsigned short*)(ws + 0);           //  5,242,880
  unsigned short* W2b   = (unsigned short*)(ws + 5242880);     //  8,388,608
  unsigned short* Weff  = (unsigned short*)(ws + 13631488);    //    131,072
  float*          beff  = (float*)(ws + 13762560);             //        128
  unsigned short* spine = (unsigned short*)(ws + 13762688);    // 41,943,040
  unsigned short* h1    = (unsigned short*)(ws + 55705728);    // 67,108,864
  unsigned short* h2    = (unsigned short*)(ws + 122814592);   // 67,108,864 -> end ~190MB

  // weight preprocessing
  f2b_kernel<<<5120, 256, 0, stream>>>(W1, (unsigned*)W1b, 1310720);
  f2b_kernel<<<8192, 256, 0, stream>>>(W2, (unsigned*)W2b, 2097152);
  weff_kernel<<<256, 256, 0, stream>>>(W3, Wd, Weff);
  beff_kernel<<<1, 64, 0, stream>>>(b3, Wd, bd, beff);

  // encoder
  encoder_kernel<<<(BATCH * SDIM) / 256, 256, 0, stream>>>(state, mean_enc, std_enc, (unsigned*)spine);

  // GEMM chain
  gemm256<<<512, 512, 0, stream>>>(spine, W1b, b1, h1, KSPINE, KSPINE / 128);
  gemm256<<<512, 512, 0, stream>>>(h1,    W2b, b2, h2, HID,    HID / 128);
  gemm_skinny<<<BATCH / 32, 128, 0, stream>>>(h2, Weff, beff, (float*)d_out);
}